// Round 4
// baseline (367.873 us; speedup 1.0000x reference)
//
#include <hip/hip_runtime.h>

#define TOK 65536
#define DM 256
#define DF 1024
#define NB 4

typedef unsigned short ushort_t;
typedef unsigned int uint32;

typedef __attribute__((ext_vector_type(8))) short bf16x8;
typedef __attribute__((ext_vector_type(4))) float f32x4;

__device__ inline ushort_t f2bf(float f) {
  union { float f; unsigned int u; } v; v.f = f;
  unsigned int u = v.u;
  unsigned int r = (u + 0x7FFFu + ((u >> 16) & 1u)) >> 16;
  return (ushort_t)r;
}
__device__ inline uint32 pack2(float a, float b) {
  return (uint32)f2bf(a) | ((uint32)f2bf(b) << 16);
}

// ---------------- kernel 0: convert w1/w2 fp32 -> bf16 + zero counts --------
__global__ __launch_bounds__(256) void prep_weights_kernel(
    const float* __restrict__ w1, const float* __restrict__ w2,
    ushort_t* __restrict__ w1b, ushort_t* __restrict__ w2b,
    int* __restrict__ counts)
{
  if (blockIdx.x == 0 && blockIdx.y == 0 && threadIdx.x < NB)
    counts[threadIdx.x] = 0;
  const int idx = blockIdx.x * 256 + threadIdx.x;   // float4 index
  const float* src = blockIdx.y ? w2 : w1;
  ushort_t* dst = blockIdx.y ? w2b : w1b;
  f32x4 v = *(const f32x4*)(src + (size_t)idx * 4);
  uint2 p;
  p.x = pack2(v.x, v.y);
  p.y = pack2(v.z, v.w);
  *(uint2*)(dst + (size_t)idx * 4) = p;
}

// ---------------- kernel 1: route tokens to per-branch lists + zero-fill ----
__global__ __launch_bounds__(256) void route_kernel(
    const int* __restrict__ b_seq, int* __restrict__ counts,
    ushort_t* __restrict__ lists, uint32* __restrict__ out32)
{
  __shared__ int s_lpos[NB];
  __shared__ int s_lbase[NB];
  __shared__ int s_b[256];
  const int tid = threadIdx.x;
  const int base = blockIdx.x * 256;
  const int token = base + tid;
  if (tid < NB) s_lpos[tid] = 0;
  __syncthreads();
  const int b = b_seq[token];
  s_b[tid] = b;
  int my = 0;
  if (b > 0) my = atomicAdd(&s_lpos[b - 1], 1);
  __syncthreads();
  if (tid < NB) s_lbase[tid] = atomicAdd(&counts[tid], s_lpos[tid]);
  __syncthreads();
  if (b > 0) lists[(b - 1) * TOK + s_lbase[b - 1] + my] = (ushort_t)token;
  #pragma unroll 4
  for (int it = 0; it < 256; ++it) {
    int flat = it * 256 + tid;
    int tl = flat >> 8;
    int j = flat & 255;
    if (s_b[tl] == 0) out32[(size_t)(base + tl) * DM + j] = 0u;
  }
}

// ---------------- kernel 2: fused FFN + LN, barrier-free inner loop ---------
// Block = 256 (4 waves). Tile M=64 tokens. Wave w: fi=w>>1 owns f-half
// (512 of D_FF), di=w&1 owns d-half (128 of D_MODEL). GEMM1 duplicated
// across di; H transform is wave-private LDS (no barrier); fi-partials of Y
// reduced once in epilogue. 3 barriers total after staging.
__global__ __launch_bounds__(256, 2) void ffn_kernel(
    const float* __restrict__ x,
    const ushort_t* __restrict__ w1b_all, const float* __restrict__ b1,
    const ushort_t* __restrict__ w2b_all, const float* __restrict__ b2,
    const float* __restrict__ gamma, const float* __restrict__ beta,
    const int* __restrict__ counts, const ushort_t* __restrict__ lists,
    float* __restrict__ out)
{
  const int id = blockIdx.x;
  const int slot = id & 7;                 // putative XCD
  const int n = slot >> 1;                 // branch -> XCD pair
  const int tile = ((id >> 3) << 1) + (slot & 1);
  const int cnt = counts[n];
  const int tile0 = tile * 64;
  if (tile0 >= cnt) return;
  const int mvalid = min(64, cnt - tile0);

  // 67584 B = 64*264 bf16 (sX) == 64*132 f32 (sY region); two regions.
  // Upper region doubles as 4x wave-private sH slices during the main loop.
  __shared__ __align__(16) unsigned char sMem[67584];
  __shared__ int s_idx[64];
  __shared__ float s_ps[2][64];
  __shared__ float s_pq[2][64];
  __shared__ float s_mu[64];
  __shared__ float s_rs[64];

  ushort_t (*sX)[264] = (ushort_t (*)[264])sMem;

  const int tid  = threadIdx.x;
  const int w    = tid >> 6;
  const int lane = tid & 63;
  const int q    = lane >> 4;
  const int lc   = lane & 15;
  const int fi   = w >> 1;      // f-half
  const int di   = w & 1;       // d-half

  ushort_t* sHw = (ushort_t*)(sMem + 33792 + w * 5120);   // [64][40] bf16

  if (tid < 64) {
    int i = tile0 + tid;
    s_idx[tid] = (int)lists[n * TOK + (i < cnt ? i : tile0)];
  }
  __syncthreads();

  // stage X tile: 64 rows x 256 fp32 -> bf16 (nontemporal: keep L2 for weights)
  #pragma unroll
  for (int it = 0; it < 16; ++it) {
    int chunk = it * 256 + tid;
    int r = chunk >> 6;
    int c = (chunk & 63) << 2;
    f32x4 v = __builtin_nontemporal_load((const f32x4*)(x + (size_t)s_idx[r] * DM + c));
    uint2 p;
    p.x = pack2(v.x, v.y);
    p.y = pack2(v.z, v.w);
    *(uint2*)(&sX[r][c]) = p;
  }
  __syncthreads();

  f32x4 yacc[4][8];     // [mi][dt]: 64 tok x 128 d partial (this wave's halves)
  #pragma unroll
  for (int mi = 0; mi < 4; ++mi)
    #pragma unroll
    for (int dt = 0; dt < 8; ++dt)
      yacc[mi][dt] = (f32x4){0.f, 0.f, 0.f, 0.f};

  const ushort_t* w1b = w1b_all + (size_t)n * DF * DM;
  const ushort_t* w2b = w2b_all + (size_t)n * DM * DF;
  const int fbase = fi * 512;

  #pragma unroll 1
  for (int fc = 0; fc < 16; ++fc) {
    const int f0 = fbase + fc * 32;

    // prefetch GEMM2 B-frags (consumed after GEMM1 -> long latency cover)
    bf16x8 wb2[8];
    #pragma unroll
    for (int dt = 0; dt < 8; ++dt)
      wb2[dt] = *(const bf16x8*)(w2b + (size_t)(di * 128 + dt * 16 + lc) * DF + f0 + q * 8);

    // ---- GEMM1: H[64 tok][32 f] over K=256, depth-1 wb1 prefetch
    f32x4 hacc[4][2];
    #pragma unroll
    for (int mi = 0; mi < 4; ++mi) {
      hacc[mi][0] = (f32x4){0.f, 0.f, 0.f, 0.f};
      hacc[mi][1] = (f32x4){0.f, 0.f, 0.f, 0.f};
    }
    const ushort_t* w1r0 = w1b + (size_t)(f0 + lc) * DM + q * 8;
    const ushort_t* w1r1 = w1b + (size_t)(f0 + 16 + lc) * DM + q * 8;
    bf16x8 nb0 = *(const bf16x8*)(w1r0);
    bf16x8 nb1 = *(const bf16x8*)(w1r1);
    #pragma unroll
    for (int ks = 0; ks < 8; ++ks) {
      bf16x8 b0 = nb0, b1f = nb1;
      if (ks < 7) {
        nb0 = *(const bf16x8*)(w1r0 + (ks + 1) * 32);
        nb1 = *(const bf16x8*)(w1r1 + (ks + 1) * 32);
      }
      #pragma unroll
      for (int mi = 0; mi < 4; ++mi) {
        bf16x8 a = *(const bf16x8*)(&sX[mi * 16 + lc][ks * 32 + q * 8]);
        hacc[mi][0] = __builtin_amdgcn_mfma_f32_16x16x32_bf16(a, b0,  hacc[mi][0], 0, 0, 0);
        hacc[mi][1] = __builtin_amdgcn_mfma_f32_16x16x32_bf16(a, b1f, hacc[mi][1], 0, 0, 0);
      }
    }

    // ---- bias + ELU, C-layout -> row-major bf16 in wave-private LDS
    const float b1v0 = b1[n * DF + f0 + lc];
    const float b1v1 = b1[n * DF + f0 + 16 + lc];
    #pragma unroll
    for (int mi = 0; mi < 4; ++mi) {
      #pragma unroll
      for (int t = 0; t < 2; ++t) {
        #pragma unroll
        for (int r = 0; r < 4; ++r) {
          float v = hacc[mi][t][r] + (t ? b1v1 : b1v0);
          v = (v > 0.f) ? v : (__expf(v) - 1.f);
          sHw[(mi * 16 + q * 4 + r) * 40 + t * 16 + lc] = f2bf(v);
        }
      }
    }
    // same-wave LDS RAW: compiler orders via lgkmcnt; no __syncthreads needed.

    // ---- GEMM2: Y[64 tok][128 d] += H[64][32] @ W2^T
    #pragma unroll
    for (int mi = 0; mi < 4; ++mi) {
      bf16x8 a = *(const bf16x8*)(sHw + (size_t)(mi * 16 + lc) * 40 + q * 8);
      #pragma unroll
      for (int dt = 0; dt < 8; ++dt)
        yacc[mi][dt] = __builtin_amdgcn_mfma_f32_16x16x32_bf16(a, wb2[dt], yacc[mi][dt], 0, 0, 0);
    }
  }

  // ================= epilogue: reduce fi-halves, LN, store ==================
  __syncthreads();          // everyone done with sX / sHw
  float* sY = (float*)(sMem + di * 33792);    // [64][132] per d-half
  if (fi == 0) {
    #pragma unroll
    for (int mi = 0; mi < 4; ++mi)
      #pragma unroll
      for (int dt = 0; dt < 8; ++dt)
        #pragma unroll
        for (int r = 0; r < 4; ++r)
          sY[(mi * 16 + q * 4 + r) * 132 + dt * 16 + lc] = yacc[mi][dt][r];
  }
  __syncthreads();

  float gv[8], bv[8];
  if (fi == 1) {
    float b2v[8];
    #pragma unroll
    for (int dt = 0; dt < 8; ++dt) {
      int idx = n * DM + di * 128 + dt * 16 + lc;
      b2v[dt] = b2[idx];
      gv[dt]  = gamma[idx];
      bv[dt]  = beta[idx];
    }
    #pragma unroll
    for (int mi = 0; mi < 4; ++mi)
      #pragma unroll
      for (int dt = 0; dt < 8; ++dt)
        #pragma unroll
        for (int r = 0; r < 4; ++r)
          yacc[mi][dt][r] += sY[(mi * 16 + q * 4 + r) * 132 + dt * 16 + lc] + b2v[dt];
    // per-token partial LN stats over this wave's 128 d-cols
    #pragma unroll
    for (int mi = 0; mi < 4; ++mi) {
      #pragma unroll
      for (int r = 0; r < 4; ++r) {
        float s = 0.f, sq = 0.f;
        #pragma unroll
        for (int dt = 0; dt < 8; ++dt) {
          float v = yacc[mi][dt][r];
          s += v; sq += v * v;
        }
        #pragma unroll
        for (int off = 1; off < 16; off <<= 1) {
          s  += __shfl_xor(s, off, 64);
          sq += __shfl_xor(sq, off, 64);
        }
        if (lc == 0) {
          int tok = mi * 16 + q * 4 + r;
          s_ps[di][tok] = s;
          s_pq[di][tok] = sq;
        }
      }
    }
  }
  __syncthreads();
  if (tid < 64) {
    float s  = s_ps[0][tid] + s_ps[1][tid];
    float sq = s_pq[0][tid] + s_pq[1][tid];
    float mu = s * (1.f / 256.f);
    float var = fmaxf(sq * (1.f / 256.f) - mu * mu, 0.f);
    s_mu[tid] = mu;
    s_rs[tid] = rsqrtf(var + 1e-12f);
  }
  __syncthreads();
  if (fi == 1) {
    #pragma unroll
    for (int mi = 0; mi < 4; ++mi) {
      #pragma unroll
      for (int r = 0; r < 4; ++r) {
        int tok = mi * 16 + q * 4 + r;
        if (tok < mvalid) {
          float mu = s_mu[tok], rs = s_rs[tok];
          size_t base = (size_t)s_idx[tok] * DM + di * 128;
          #pragma unroll
          for (int dt = 0; dt < 8; ++dt) {
            float v = (yacc[mi][dt][r] - mu) * rs * gv[dt] + bv[dt];
            __builtin_nontemporal_store(v, out + base + dt * 16 + lc);
          }
        }
      }
    }
  }
}

extern "C" void kernel_launch(void* const* d_in, const int* in_sizes, int n_in,
                              void* d_out, int out_size, void* d_ws, size_t ws_size,
                              hipStream_t stream) {
  const float* x     = (const float*)d_in[0];
  const int*   b_seq = (const int*)d_in[1];
  const float* w1    = (const float*)d_in[2];
  const float* b1    = (const float*)d_in[3];
  const float* w2    = (const float*)d_in[4];
  const float* b2    = (const float*)d_in[5];
  const float* gamma = (const float*)d_in[6];
  const float* beta  = (const float*)d_in[7];
  float* out = (float*)d_out;

  int* counts = (int*)d_ws;
  ushort_t* lists = (ushort_t*)((char*)d_ws + 256);                 // 512 KB
  ushort_t* w1b = (ushort_t*)((char*)d_ws + 256 + 512 * 1024);      // 2 MB
  ushort_t* w2b = w1b + (size_t)NB * DF * DM;                       // 2 MB

  hipLaunchKernelGGL(prep_weights_kernel, dim3(1024, 2), dim3(256), 0, stream,
                     w1, w2, w1b, w2b, counts);
  hipLaunchKernelGGL(route_kernel, dim3(TOK / 256), dim3(256), 0, stream,
                     b_seq, counts, lists, (uint32*)d_out);
  hipLaunchKernelGGL(ffn_kernel, dim3(4096), dim3(256), 0, stream,
                     x, w1b, b1, w2b, b2, gamma, beta, counts, lists, out);
}

// Round 5
// 259.422 us; speedup vs baseline: 1.4180x; 1.4180x over previous
//
#include <hip/hip_runtime.h>

#define TOK 65536
#define DM 256
#define DF 1024
#define NB 4

typedef unsigned short ushort_t;
typedef unsigned int uint32;

typedef __attribute__((ext_vector_type(8))) short bf16x8;
typedef __attribute__((ext_vector_type(4))) float f32x4;

__device__ inline ushort_t f2bf(float f) {
  union { float f; unsigned int u; } v; v.f = f;
  unsigned int u = v.u;
  unsigned int r = (u + 0x7FFFu + ((u >> 16) & 1u)) >> 16;
  return (ushort_t)r;
}
__device__ inline uint32 pack2(float a, float b) {
  return (uint32)f2bf(a) | ((uint32)f2bf(b) << 16);
}

// async global->LDS DMA, 16 B per lane. LDS dest = wave-uniform base + lane*16.
__device__ __forceinline__ void dma16(const ushort_t* g, ushort_t* lds) {
  __builtin_amdgcn_global_load_lds(
      (const __attribute__((address_space(1))) unsigned int*)(const void*)g,
      (__attribute__((address_space(3))) unsigned int*)(void*)lds,
      16, 0, 0);
}

// ---------------- kernel 0: convert w1/w2 fp32 -> bf16 + zero counts --------
__global__ __launch_bounds__(256) void prep_weights_kernel(
    const float* __restrict__ w1, const float* __restrict__ w2,
    ushort_t* __restrict__ w1b, ushort_t* __restrict__ w2b,
    int* __restrict__ counts)
{
  if (blockIdx.x == 0 && blockIdx.y == 0 && threadIdx.x < NB)
    counts[threadIdx.x] = 0;
  const int idx = blockIdx.x * 256 + threadIdx.x;   // float4 index
  const float* src = blockIdx.y ? w2 : w1;
  ushort_t* dst = blockIdx.y ? w2b : w1b;
  f32x4 v = *(const f32x4*)(src + (size_t)idx * 4);
  uint2 p;
  p.x = pack2(v.x, v.y);
  p.y = pack2(v.z, v.w);
  *(uint2*)(dst + (size_t)idx * 4) = p;
}

// ---------------- kernel 1: route tokens to per-branch lists + zero-fill ----
__global__ __launch_bounds__(256) void route_kernel(
    const int* __restrict__ b_seq, int* __restrict__ counts,
    ushort_t* __restrict__ lists, uint32* __restrict__ out32)
{
  __shared__ int s_lpos[NB];
  __shared__ int s_lbase[NB];
  __shared__ int s_b[256];
  const int tid = threadIdx.x;
  const int base = blockIdx.x * 256;
  const int token = base + tid;
  if (tid < NB) s_lpos[tid] = 0;
  __syncthreads();
  const int b = b_seq[token];
  s_b[tid] = b;
  int my = 0;
  if (b > 0) my = atomicAdd(&s_lpos[b - 1], 1);
  __syncthreads();
  if (tid < NB) s_lbase[tid] = atomicAdd(&counts[tid], s_lpos[tid]);
  __syncthreads();
  if (b > 0) lists[(b - 1) * TOK + s_lbase[b - 1] + my] = (ushort_t)token;
  #pragma unroll 4
  for (int it = 0; it < 256; ++it) {
    int flat = it * 256 + tid;
    int tl = flat >> 8;
    int j = flat & 255;
    if (s_b[tl] == 0) out32[(size_t)(base + tl) * DM + j] = 0u;
  }
}

// ---------------- kernel 2: fused FFN + LN, DMA-staged weights --------------
// Block = 256 (4 waves), M=64 tokens, 16 chunks of F=64.
// X A-frags live in registers (loaded once). Weights stream through LDS via
// global_load_lds with XOR-swizzled layout. GEMM1: wave owns 16 f-cols.
// GEMM2: wave owns 64 d-cols. 2 barriers/chunk; each drains one DMA stream
// that was covered by the opposite GEMM's compute.
__global__ __launch_bounds__(256, 2) void ffn_kernel(
    const float* __restrict__ x,
    const ushort_t* __restrict__ w1b_all, const float* __restrict__ b1,
    const ushort_t* __restrict__ w2b_all, const float* __restrict__ b2,
    const float* __restrict__ gamma, const float* __restrict__ beta,
    const int* __restrict__ counts, const ushort_t* __restrict__ lists,
    float* __restrict__ out)
{
  const int id = blockIdx.x;
  const int slot = id & 7;                 // putative XCD
  const int n = slot >> 1;                 // branch -> XCD pair
  const int tile = ((id >> 3) << 1) + (slot & 1);
  const int cnt = counts[n];
  const int tile0 = tile * 64;
  if (tile0 >= cnt) return;
  const int mvalid = min(64, cnt - tile0);

  // sWbuf: 64 KB. During staging: sX view [64][264]. During loop:
  //   sW1 = sWbuf[0:16384)  : W1 chunk [64 f][256 k], XOR-swizzled
  //   sW2 = sWbuf[16384:)   : W2 chunk [256 d][64 f], XOR-swizzled
  __shared__ __align__(16) ushort_t sWbuf[32768];
  __shared__ __align__(16) ushort_t sH[64][72];
  __shared__ int s_idx[64];
  __shared__ float s_ps[4][64];
  __shared__ float s_pq[4][64];
  __shared__ float s_mu[64];
  __shared__ float s_rs[64];

  ushort_t* sW1 = sWbuf;
  ushort_t* sW2 = sWbuf + 16384;
  ushort_t (*sX)[264] = (ushort_t (*)[264])sWbuf;

  const int tid  = threadIdx.x;
  const int w    = tid >> 6;
  const int lane = tid & 63;
  const int q    = lane >> 4;
  const int lc   = lane & 15;

  const ushort_t* w1b = w1b_all + (size_t)n * DF * DM;
  const ushort_t* w2b = w2b_all + (size_t)n * DM * DF;

  if (tid < 64) {
    int i = tile0 + tid;
    s_idx[tid] = (int)lists[n * TOK + (i < cnt ? i : tile0)];
  }
  __syncthreads();

  // ---- stage X tile: 64 rows x 256 fp32 -> bf16 in sX (aliases sWbuf)
  #pragma unroll
  for (int it = 0; it < 16; ++it) {
    int chunk = it * 256 + tid;
    int r = chunk >> 6;
    int c = (chunk & 63) << 2;
    f32x4 v = *(const f32x4*)(x + (size_t)s_idx[r] * DM + c);
    uint2 p;
    p.x = pack2(v.x, v.y);
    p.y = pack2(v.z, v.w);
    *(uint2*)(&sX[r][c]) = p;
  }
  __syncthreads();

  // ---- X A-frags to registers: all 64 tokens, K=256  (128 VGPRs)
  bf16x8 xfrag[4][8];
  #pragma unroll
  for (int mi = 0; mi < 4; ++mi)
    #pragma unroll
    for (int ks = 0; ks < 8; ++ks)
      xfrag[mi][ks] = *(const bf16x8*)(&sX[mi * 16 + lc][ks * 32 + q * 8]);
  __syncthreads();           // all sX reads done; sWbuf free for DMA

  // ---- DMA W1 chunk 0 into sW1 (8 instrs/wave, 1 KB each)
  {
    const ushort_t* basew1 = w1b;    // f0 = 0: 64 rows x 256 contiguous
    #pragma unroll
    for (int j = 0; j < 8; ++j) {
      int i = w * 8 + j;
      int s = i * 64 + lane;         // 16B slot index
      int r = s >> 5;                // row 0..63
      int cp = s & 31;               // swizzled 16B-chunk position
      int c16 = cp ^ (r & 31);       // source chunk col
      dma16(basew1 + r * 256 + c16 * 8, sW1 + i * 512);
    }
  }
  __syncthreads();           // W1 c0 resident

  f32x4 yacc[4][4];
  #pragma unroll
  for (int mi = 0; mi < 4; ++mi)
    #pragma unroll
    for (int di = 0; di < 4; ++di)
      yacc[mi][di] = (f32x4){0.f, 0.f, 0.f, 0.f};

  #pragma unroll 1
  for (int fc = 0; fc < 16; ++fc) {
    // ---- issue W2 DMA for this chunk (drains at mid-barrier, covered by GEMM1)
    {
      const ushort_t* basew2 = w2b + fc * 64;
      #pragma unroll
      for (int j = 0; j < 8; ++j) {
        int i = w * 8 + j;
        int s = i * 64 + lane;       // 16B slot
        int d = s >> 3;              // d-row 0..255 (128 B rows)
        int cp = s & 7;
        int c16 = cp ^ (d & 7);
        dma16(basew2 + (size_t)d * DF + c16 * 8, sW2 + i * 512);
      }
    }

    const float b1v = b1[n * DF + fc * 64 + w * 16 + lc];

    // ---- GEMM1: H[64 tok x 16 f-strip] over K=256, A from regs, B from sW1
    f32x4 hacc[4];
    #pragma unroll
    for (int mi = 0; mi < 4; ++mi) hacc[mi] = (f32x4){0.f, 0.f, 0.f, 0.f};
    {
      const int r = w * 16 + lc;     // W1 local row (this wave's f-col)
      #pragma unroll
      for (int ks = 0; ks < 8; ++ks) {
        int cp = (ks * 4 + q) ^ (r & 31);
        bf16x8 bf = *(const bf16x8*)(sW1 + r * 256 + cp * 8);
        #pragma unroll
        for (int mi = 0; mi < 4; ++mi)
          hacc[mi] = __builtin_amdgcn_mfma_f32_16x16x32_bf16(xfrag[mi][ks], bf, hacc[mi], 0, 0, 0);
      }
    }
    // ---- bias + ELU, C-layout -> row-major bf16 in shared sH
    #pragma unroll
    for (int mi = 0; mi < 4; ++mi) {
      #pragma unroll
      for (int r4 = 0; r4 < 4; ++r4) {
        float v = hacc[mi][r4] + b1v;
        v = (v > 0.f) ? v : (__expf(v) - 1.f);
        sH[mi * 16 + q * 4 + r4][w * 16 + lc] = f2bf(v);
      }
    }
    __syncthreads();   // mid: sH ready, W2 DMA drained, sW1 reads done

    // ---- issue W1 DMA for next chunk (drains at end-barrier, covered by GEMM2)
    if (fc < 15) {
      const ushort_t* basew1 = w1b + (size_t)(fc + 1) * 64 * 256;
      #pragma unroll
      for (int j = 0; j < 8; ++j) {
        int i = w * 8 + j;
        int s = i * 64 + lane;
        int r = s >> 5;
        int cp = s & 31;
        int c16 = cp ^ (r & 31);
        dma16(basew1 + r * 256 + c16 * 8, sW1 + i * 512);
      }
    }

    // ---- GEMM2: Y[64 tok x 64 d-strip] += H @ W2^T, B from sW2
    #pragma unroll
    for (int ks = 0; ks < 2; ++ks) {
      bf16x8 af[4];
      #pragma unroll
      for (int mi = 0; mi < 4; ++mi)
        af[mi] = *(const bf16x8*)(&sH[mi * 16 + lc][ks * 32 + q * 8]);
      #pragma unroll
      for (int di = 0; di < 4; ++di) {
        int dl = w * 64 + di * 16 + lc;      // W2 local d-row
        int cp = (ks * 4 + q) ^ (dl & 7);
        bf16x8 bf = *(const bf16x8*)(sW2 + dl * 64 + cp * 8);
        #pragma unroll
        for (int mi = 0; mi < 4; ++mi)
          yacc[mi][di] = __builtin_amdgcn_mfma_f32_16x16x32_bf16(af[mi], bf, yacc[mi][di], 0, 0, 0);
      }
    }
    __syncthreads();   // end: W1(next) drained, sW2/sH reads done
  }

  // ---- epilogue: +b2, LayerNorm stats (cross-wave), gamma/beta, scatter out
  float b2v[4], gv[4], bv[4];
  #pragma unroll
  for (int di = 0; di < 4; ++di) {
    int dcol = w * 64 + di * 16 + lc;
    b2v[di] = b2[n * DM + dcol];
    gv[di]  = gamma[n * DM + dcol];
    bv[di]  = beta[n * DM + dcol];
  }
  #pragma unroll
  for (int mi = 0; mi < 4; ++mi)
    #pragma unroll
    for (int di = 0; di < 4; ++di)
      #pragma unroll
      for (int r4 = 0; r4 < 4; ++r4)
        yacc[mi][di][r4] += b2v[di];

  #pragma unroll
  for (int mi = 0; mi < 4; ++mi) {
    #pragma unroll
    for (int r4 = 0; r4 < 4; ++r4) {
      float s = 0.f, sq = 0.f;
      #pragma unroll
      for (int di = 0; di < 4; ++di) {
        float v = yacc[mi][di][r4];
        s += v; sq += v * v;
      }
      #pragma unroll
      for (int off = 1; off < 16; off <<= 1) {
        s  += __shfl_xor(s, off, 64);
        sq += __shfl_xor(sq, off, 64);
      }
      if (lc == 0) {
        int m = mi * 16 + q * 4 + r4;
        s_ps[w][m] = s;
        s_pq[w][m] = sq;
      }
    }
  }
  __syncthreads();
  if (tid < 64) {
    float s  = s_ps[0][tid] + s_ps[1][tid] + s_ps[2][tid] + s_ps[3][tid];
    float sq = s_pq[0][tid] + s_pq[1][tid] + s_pq[2][tid] + s_pq[3][tid];
    float mu = s * (1.f / 256.f);
    float var = fmaxf(sq * (1.f / 256.f) - mu * mu, 0.f);
    s_mu[tid] = mu;
    s_rs[tid] = rsqrtf(var + 1e-12f);
  }
  __syncthreads();

  #pragma unroll
  for (int mi = 0; mi < 4; ++mi) {
    #pragma unroll
    for (int r4 = 0; r4 < 4; ++r4) {
      int m = mi * 16 + q * 4 + r4;
      if (m < mvalid) {
        float mu = s_mu[m], rs = s_rs[m];
        size_t rowbase = (size_t)s_idx[m] * DM;
        #pragma unroll
        for (int di = 0; di < 4; ++di) {
          int dcol = w * 64 + di * 16 + lc;
          float v = (yacc[mi][di][r4] - mu) * rs * gv[di] + bv[di];
          out[rowbase + dcol] = v;
        }
      }
    }
  }
}

extern "C" void kernel_launch(void* const* d_in, const int* in_sizes, int n_in,
                              void* d_out, int out_size, void* d_ws, size_t ws_size,
                              hipStream_t stream) {
  const float* x     = (const float*)d_in[0];
  const int*   b_seq = (const int*)d_in[1];
  const float* w1    = (const float*)d_in[2];
  const float* b1    = (const float*)d_in[3];
  const float* w2    = (const float*)d_in[4];
  const float* b2    = (const float*)d_in[5];
  const float* gamma = (const float*)d_in[6];
  const float* beta  = (const float*)d_in[7];
  float* out = (float*)d_out;

  int* counts = (int*)d_ws;
  ushort_t* lists = (ushort_t*)((char*)d_ws + 256);                 // 512 KB
  ushort_t* w1b = (ushort_t*)((char*)d_ws + 256 + 512 * 1024);      // 2 MB
  ushort_t* w2b = w1b + (size_t)NB * DF * DM;                       // 2 MB

  hipLaunchKernelGGL(prep_weights_kernel, dim3(1024, 2), dim3(256), 0, stream,
                     w1, w2, w1b, w2b, counts);
  hipLaunchKernelGGL(route_kernel, dim3(TOK / 256), dim3(256), 0, stream,
                     b_seq, counts, lists, (uint32*)d_out);
  hipLaunchKernelGGL(ffn_kernel, dim3(4096), dim3(256), 0, stream,
                     x, w1b, b1, w2b, b2, gamma, beta, counts, lists, out);
}

// Round 6
// 243.789 us; speedup vs baseline: 1.5090x; 1.0641x over previous
//
#include <hip/hip_runtime.h>

#define TOK 65536
#define DM 256
#define DF 1024
#define NB 4

typedef unsigned short ushort_t;
typedef unsigned int uint32;

typedef __attribute__((ext_vector_type(8))) short bf16x8;
typedef __attribute__((ext_vector_type(4))) float f32x4;

__device__ inline ushort_t f2bf(float f) {
  union { float f; unsigned int u; } v; v.f = f;
  unsigned int u = v.u;
  unsigned int r = (u + 0x7FFFu + ((u >> 16) & 1u)) >> 16;
  return (ushort_t)r;
}
__device__ inline uint32 pack2(float a, float b) {
  return (uint32)f2bf(a) | ((uint32)f2bf(b) << 16);
}

// async global->LDS DMA, 16 B/lane: LDS dest = wave-uniform base + lane*16.
__device__ __forceinline__ void dma16(const ushort_t* g, ushort_t* lds) {
  __builtin_amdgcn_global_load_lds(
      (const __attribute__((address_space(1))) unsigned int*)(const void*)g,
      (__attribute__((address_space(3))) unsigned int*)(void*)lds,
      16, 0, 0);
}

// ---------------- kernel 0: convert w1/w2 fp32 -> bf16 + zero counts --------
__global__ __launch_bounds__(256) void prep_weights_kernel(
    const float* __restrict__ w1, const float* __restrict__ w2,
    ushort_t* __restrict__ w1b, ushort_t* __restrict__ w2b,
    int* __restrict__ counts)
{
  if (blockIdx.x == 0 && blockIdx.y == 0 && threadIdx.x < NB)
    counts[threadIdx.x] = 0;
  const int idx = blockIdx.x * 256 + threadIdx.x;
  const float* src = blockIdx.y ? w2 : w1;
  ushort_t* dst = blockIdx.y ? w2b : w1b;
  f32x4 v = *(const f32x4*)(src + (size_t)idx * 4);
  uint2 p;
  p.x = pack2(v.x, v.y);
  p.y = pack2(v.z, v.w);
  *(uint2*)(dst + (size_t)idx * 4) = p;
}

// ---------------- kernel 1: route tokens to per-branch lists + zero-fill ----
__global__ __launch_bounds__(256) void route_kernel(
    const int* __restrict__ b_seq, int* __restrict__ counts,
    ushort_t* __restrict__ lists, uint32* __restrict__ out32)
{
  __shared__ int s_lpos[NB];
  __shared__ int s_lbase[NB];
  __shared__ int s_b[256];
  const int tid = threadIdx.x;
  const int base = blockIdx.x * 256;
  const int token = base + tid;
  if (tid < NB) s_lpos[tid] = 0;
  __syncthreads();
  const int b = b_seq[token];
  s_b[tid] = b;
  int my = 0;
  if (b > 0) my = atomicAdd(&s_lpos[b - 1], 1);
  __syncthreads();
  if (tid < NB) s_lbase[tid] = atomicAdd(&counts[tid], s_lpos[tid]);
  __syncthreads();
  if (b > 0) lists[(b - 1) * TOK + s_lbase[b - 1] + my] = (ushort_t)token;
  #pragma unroll 4
  for (int it = 0; it < 256; ++it) {
    int flat = it * 256 + tid;
    int tl = flat >> 8;
    int j = flat & 255;
    if (s_b[tl] == 0) out32[(size_t)(base + tl) * DM + j] = 0u;
  }
}

// ---------------- kernel 2: fused FFN + LN, pipelined DMA, raw barriers -----
// Block = 4 waves, M=64 tokens, 32 chunks of F=32. Weights double-buffered in
// LDS via global_load_lds issued one full chunk ahead; barriers are raw
// s_barrier with explicit waitcnt so prefetch is never force-drained.
// GEMM1: wave (fi=w&1, mh=w>>1) computes H[32 tok x 16 f].
// GEMM2: wave (dh=w&1, mh)      computes Y[32 tok x 128 d].
__global__ __launch_bounds__(256, 2) void ffn_kernel(
    const float* __restrict__ x,
    const ushort_t* __restrict__ w1b_all, const float* __restrict__ b1,
    const ushort_t* __restrict__ w2b_all, const float* __restrict__ b2,
    const float* __restrict__ gamma, const float* __restrict__ beta,
    const int* __restrict__ counts, const ushort_t* __restrict__ lists,
    float* __restrict__ out)
{
  const int id = blockIdx.x;
  const int slot = id & 7;
  const int n = slot >> 1;
  const int tile = ((id >> 3) << 1) + (slot & 1);
  const int cnt = counts[n];
  const int tile0 = tile * 64;
  if (tile0 >= cnt) return;
  const int mvalid = min(64, cnt - tile0);

  // 64 KB: sW1 bufs at [0,16K),[16K,32K); sW2 bufs at [32K,48K),[48K,64K).
  // Prologue aliases the region as sX[64][264] (33.8 KB).
  __shared__ __align__(16) ushort_t sWmem[32768];
  __shared__ __align__(16) ushort_t sH[64][40];
  __shared__ float sB1[DF];
  __shared__ int s_idx[64];
  __shared__ float s_ps[2][64];
  __shared__ float s_pq[2][64];
  __shared__ float s_mu[64];
  __shared__ float s_rs[64];

  ushort_t (*sX)[264] = (ushort_t (*)[264])sWmem;

  const int tid  = threadIdx.x;
  const int wv   = tid >> 6;
  const int lane = tid & 63;
  const int q    = lane >> 4;
  const int lc   = lane & 15;
  const int fi   = wv & 1;      // GEMM1 f-sub (16 cols of the 32-chunk)
  const int mh   = wv >> 1;     // token half (32 rows)
  const int dh   = wv & 1;      // GEMM2 d-half (128 cols)

  const ushort_t* w1b = w1b_all + (size_t)n * DF * DM;
  const ushort_t* w2b = w2b_all + (size_t)n * DM * DF;

  if (tid < 64) {
    int i = tile0 + tid;
    s_idx[tid] = (int)lists[n * TOK + (i < cnt ? i : tile0)];
  }
  // stage b1 slice (1024 floats)
  {
    f32x4 v = *(const f32x4*)(b1 + n * DF + tid * 4);
    *(f32x4*)(sB1 + tid * 4) = v;
  }
  __syncthreads();

  // ---- stage X tile 64x256 fp32 -> bf16 into sX (aliases weight bufs)
  #pragma unroll
  for (int it = 0; it < 16; ++it) {
    int chunk = it * 256 + tid;
    int r = chunk >> 6;
    int c = (chunk & 63) << 2;
    f32x4 v = *(const f32x4*)(x + (size_t)s_idx[r] * DM + c);
    uint2 p;
    p.x = pack2(v.x, v.y);
    p.y = pack2(v.z, v.w);
    *(uint2*)(&sX[r][c]) = p;
  }
  __syncthreads();

  // ---- X A-frags to regs: this wave's 32 tokens x K=256 (32 VGPR)
  bf16x8 xfrag[2][8];
  #pragma unroll
  for (int mi2 = 0; mi2 < 2; ++mi2)
    #pragma unroll
    for (int ks = 0; ks < 8; ++ks)
      xfrag[mi2][ks] = *(const bf16x8*)(&sX[mh * 32 + mi2 * 16 + lc][ks * 32 + q * 8]);
  __syncthreads();        // sX dead; weight bufs free

  // DMA issue for chunk fc1 into buffer fc1&1. 4+4 instrs per wave, 1 KB each.
  auto issue_dma = [&](int fc1) {
    const int b = fc1 & 1;
    ushort_t* dW1 = sWmem + b * 8192;
    ushort_t* dW2 = sWmem + 16384 + b * 8192;
    const ushort_t* g1 = w1b + (size_t)(fc1 * 32) * DM;
    const ushort_t* g2 = w2b + fc1 * 32;
    #pragma unroll
    for (int j = 0; j < 4; ++j) {
      int i = wv * 4 + j;
      int s = i * 64 + lane;
      // W1: [32 f][256 k]; row r = s>>5, chunk pos cp = s&31, swizzle on src
      int r1 = s >> 5, cp1 = s & 31;
      dma16(g1 + (size_t)r1 * DM + (size_t)(cp1 ^ (r1 & 31)) * 8, dW1 + i * 512);
      // W2: [256 d][32 f]; row d = s>>2, cp = s&3
      int d2 = s >> 2, cp2 = s & 3;
      dma16(g2 + (size_t)d2 * DF + (size_t)(cp2 ^ (d2 & 3)) * 8, dW2 + i * 512);
    }
  };

  issue_dma(0);

  f32x4 yacc[2][8];       // [mi2][di]: 32 tok x 128 d
  #pragma unroll
  for (int mi2 = 0; mi2 < 2; ++mi2)
    #pragma unroll
    for (int di = 0; di < 8; ++di)
      yacc[mi2][di] = (f32x4){0.f, 0.f, 0.f, 0.f};

  #pragma unroll 1
  for (int fc = 0; fc < 32; ++fc) {
    const int b = fc & 1;
    const ushort_t* cW1 = sWmem + b * 8192;
    const ushort_t* cW2 = sWmem + 16384 + b * 8192;

    // entry barrier: drain the chunk-old prefetch (covered), sync buffers
    __builtin_amdgcn_sched_barrier(0);
    __builtin_amdgcn_s_waitcnt(0x0070);     // vmcnt(0) lgkmcnt(0)
    __builtin_amdgcn_s_barrier();
    __builtin_amdgcn_sched_barrier(0);

    // prefetch next chunk into the other buffers (drains at NEXT entry)
    if (fc < 31) issue_dma(fc + 1);

    // ---- GEMM1: H[32 tok x 16 f] over K=256; B-frags reused over 2 mi2
    f32x4 hacc[2];
    hacc[0] = (f32x4){0.f, 0.f, 0.f, 0.f};
    hacc[1] = (f32x4){0.f, 0.f, 0.f, 0.f};
    {
      const int r = fi * 16 + lc;           // W1 local row
      #pragma unroll
      for (int ks = 0; ks < 8; ++ks) {
        int cp = (ks * 4 + q) ^ (r & 31);
        bf16x8 bf = *(const bf16x8*)(cW1 + r * 256 + cp * 8);
        hacc[0] = __builtin_amdgcn_mfma_f32_16x16x32_bf16(xfrag[0][ks], bf, hacc[0], 0, 0, 0);
        hacc[1] = __builtin_amdgcn_mfma_f32_16x16x32_bf16(xfrag[1][ks], bf, hacc[1], 0, 0, 0);
      }
    }
    // ---- bias + ELU -> sH (C-layout -> row-major)
    const float b1v = sB1[fc * 32 + fi * 16 + lc];
    #pragma unroll
    for (int mi2 = 0; mi2 < 2; ++mi2) {
      #pragma unroll
      for (int r4 = 0; r4 < 4; ++r4) {
        float v = hacc[mi2][r4] + b1v;
        v = (v > 0.f) ? v : (__expf(v) - 1.f);
        sH[mh * 32 + mi2 * 16 + q * 4 + r4][fi * 16 + lc] = f2bf(v);
      }
    }

    // mid barrier: publish sH; do NOT drain vmcnt (prefetch stays in flight)
    __builtin_amdgcn_sched_barrier(0);
    __builtin_amdgcn_s_waitcnt(0xC07F);     // lgkmcnt(0), vmcnt untouched
    __builtin_amdgcn_s_barrier();
    __builtin_amdgcn_sched_barrier(0);

    // ---- GEMM2: Y[32 tok x 128 d] += H[32 x 32] @ W2^T; B reused over 2 mi2
    bf16x8 af[2];
    #pragma unroll
    for (int mi2 = 0; mi2 < 2; ++mi2)
      af[mi2] = *(const bf16x8*)(&sH[mh * 32 + mi2 * 16 + lc][q * 8]);
    #pragma unroll
    for (int di = 0; di < 8; ++di) {
      int d = dh * 128 + di * 16 + lc;
      int cp = q ^ (d & 3);
      bf16x8 bf = *(const bf16x8*)(cW2 + d * 32 + cp * 8);
      yacc[0][di] = __builtin_amdgcn_mfma_f32_16x16x32_bf16(af[0], bf, yacc[0][di], 0, 0, 0);
      yacc[1][di] = __builtin_amdgcn_mfma_f32_16x16x32_bf16(af[1], bf, yacc[1][di], 0, 0, 0);
    }
  }

  // ================= epilogue: +b2, LN stats, gamma/beta, store =============
  __syncthreads();
  float b2v[8], gv[8], bv[8];
  #pragma unroll
  for (int di = 0; di < 8; ++di) {
    int dcol = n * DM + dh * 128 + di * 16 + lc;
    b2v[di] = b2[dcol];
    gv[di]  = gamma[dcol];
    bv[di]  = beta[dcol];
  }
  #pragma unroll
  for (int mi2 = 0; mi2 < 2; ++mi2)
    #pragma unroll
    for (int di = 0; di < 8; ++di)
      #pragma unroll
      for (int r4 = 0; r4 < 4; ++r4)
        yacc[mi2][di][r4] += b2v[di];

  #pragma unroll
  for (int mi2 = 0; mi2 < 2; ++mi2) {
    #pragma unroll
    for (int r4 = 0; r4 < 4; ++r4) {
      float s = 0.f, sq = 0.f;
      #pragma unroll
      for (int di = 0; di < 8; ++di) {
        float v = yacc[mi2][di][r4];
        s += v; sq += v * v;
      }
      #pragma unroll
      for (int off = 1; off < 16; off <<= 1) {
        s  += __shfl_xor(s, off, 64);
        sq += __shfl_xor(sq, off, 64);
      }
      if (lc == 0) {
        int tok = mh * 32 + mi2 * 16 + q * 4 + r4;
        s_ps[dh][tok] = s;
        s_pq[dh][tok] = sq;
      }
    }
  }
  __syncthreads();
  if (tid < 64) {
    float s  = s_ps[0][tid] + s_ps[1][tid];
    float sq = s_pq[0][tid] + s_pq[1][tid];
    float mu = s * (1.f / 256.f);
    float var = fmaxf(sq * (1.f / 256.f) - mu * mu, 0.f);
    s_mu[tid] = mu;
    s_rs[tid] = rsqrtf(var + 1e-12f);
  }
  __syncthreads();

  #pragma unroll
  for (int mi2 = 0; mi2 < 2; ++mi2) {
    #pragma unroll
    for (int r4 = 0; r4 < 4; ++r4) {
      int tok = mh * 32 + mi2 * 16 + q * 4 + r4;
      if (tok < mvalid) {
        float mu = s_mu[tok], rs = s_rs[tok];
        size_t rowbase = (size_t)s_idx[tok] * DM + dh * 128;
        #pragma unroll
        for (int di = 0; di < 8; ++di) {
          float v = (yacc[mi2][di][r4] - mu) * rs * gv[di] + bv[di];
          out[rowbase + di * 16 + lc] = v;
        }
      }
    }
  }
}

extern "C" void kernel_launch(void* const* d_in, const int* in_sizes, int n_in,
                              void* d_out, int out_size, void* d_ws, size_t ws_size,
                              hipStream_t stream) {
  const float* x     = (const float*)d_in[0];
  const int*   b_seq = (const int*)d_in[1];
  const float* w1    = (const float*)d_in[2];
  const float* b1    = (const float*)d_in[3];
  const float* w2    = (const float*)d_in[4];
  const float* b2    = (const float*)d_in[5];
  const float* gamma = (const float*)d_in[6];
  const float* beta  = (const float*)d_in[7];
  float* out = (float*)d_out;

  int* counts = (int*)d_ws;
  ushort_t* lists = (ushort_t*)((char*)d_ws + 256);                 // 512 KB
  ushort_t* w1b = (ushort_t*)((char*)d_ws + 256 + 512 * 1024);      // 2 MB
  ushort_t* w2b = w1b + (size_t)NB * DF * DM;                       // 2 MB

  hipLaunchKernelGGL(prep_weights_kernel, dim3(1024, 2), dim3(256), 0, stream,
                     w1, w2, w1b, w2b, counts);
  hipLaunchKernelGGL(route_kernel, dim3(TOK / 256), dim3(256), 0, stream,
                     b_seq, counts, lists, (uint32*)d_out);
  hipLaunchKernelGGL(ffn_kernel, dim3(4096), dim3(256), 0, stream,
                     x, w1b, b1, w2b, b2, gamma, beta, counts, lists, out);
}